// Round 5
// baseline (225.039 us; speedup 1.0000x reference)
//
#include <hip/hip_runtime.h>
#include <math.h>

#define NN 1024

typedef __attribute__((ext_vector_type(8))) short bf16x8;
typedef __attribute__((ext_vector_type(4))) float f32x4;
typedef __attribute__((ext_vector_type(4))) unsigned int u32x4;

__device__ __forceinline__ float sigmoidf_(float x) { return 1.0f / (1.0f + __expf(-x)); }

// RNE bf16 round; pack two floats into one dword (lo = a, hi = b)
__device__ __forceinline__ unsigned int pk_bf16(float a, float b) {
    unsigned int ua = __float_as_uint(a), ub = __float_as_uint(b);
    ua += 0x7fffu + ((ua >> 16) & 1u);
    ub += 0x7fffu + ((ub >> 16) & 1u);
    return (ua >> 16) | (ub & 0xffff0000u);
}
__device__ __forceinline__ unsigned short f2bf_rne(float a) {
    unsigned int ua = __float_as_uint(a);
    ua += 0x7fffu + ((ua >> 16) & 1u);
    return (unsigned short)(ua >> 16);
}

struct Ctx {
    bf16x8 w2a0, w2a1, w3a0, w3a1;
    f32x4 b2v0, b2v1, b3v0, b3v1;   // biases folded into MFMA C operand
    float wj8[8];
};

__device__ __forceinline__ void make_ctx(Ctx& c, int p, int q,
    const float* __restrict__ W1, const float* __restrict__ W2,
    const float* __restrict__ b2, const float* __restrict__ W3,
    const float* __restrict__ b3)
{
    union FU { bf16x8 v; unsigned short s[8]; } t0, t1, t2, t3;
#pragma unroll
    for (int jj = 0; jj < 8; jj++) {
        int k = q * 8 + jj;
        t0.s[jj] = f2bf_rne(W2[p * 32 + k]);
        t1.s[jj] = f2bf_rne(W2[(16 + p) * 32 + k]);
        t2.s[jj] = f2bf_rne(W3[p * 32 + k]);
        t3.s[jj] = f2bf_rne(W3[(16 + p) * 32 + k]);
        c.wj8[jj] = W1[k * 67 + 64];
    }
    c.w2a0 = t0.v; c.w2a1 = t1.v; c.w3a0 = t2.v; c.w3a1 = t3.v;
#pragma unroll
    for (int r = 0; r < 4; r++) {
        c.b2v0[r] = b2[q * 4 + r];  c.b2v1[r] = b2[16 + q * 4 + r];
        c.b3v0[r] = b3[q * 4 + r];  c.b3v1[r] = b3[16 + q * 4 + r];
    }
}

__device__ __forceinline__ void gru_row(int s, float hval, float mval, float bj,
    const float* __restrict__ Wih, const float* __restrict__ bih,
    const float* __restrict__ bhh, const float* __restrict__ W1,
    const float* __restrict__ b1, float& hn, float& uacc, float& vacc)
{
    float g0 = bih[s], g1 = bih[32 + s], g2 = bih[64 + s];
#pragma unroll 8
    for (int k = 0; k < 32; k++) {
        float hk = __shfl(hval, k, 32);
        float mk = __shfl(mval, k, 32);
        g0 = fmaf(Wih[s * 64 + k],             hk, g0);
        g0 = fmaf(Wih[s * 64 + 32 + k],        mk, g0);
        g1 = fmaf(Wih[(32 + s) * 64 + k],      hk, g1);
        g1 = fmaf(Wih[(32 + s) * 64 + 32 + k], mk, g1);
        g2 = fmaf(Wih[(64 + s) * 64 + k],      hk, g2);
        g2 = fmaf(Wih[(64 + s) * 64 + 32 + k], mk, g2);
    }
    float r = sigmoidf_(g0 + bhh[s]);
    float z = sigmoidf_(g1 + bhh[32 + s]);
    float n = tanhf(g2 + r * bhh[64 + s]);
    hn = (1.0f - z) * n;
    float ua = bj * W1[s * 67 + 65];
    float va = fmaf(bj, W1[s * 67 + 66], b1[s]);
#pragma unroll 8
    for (int k = 0; k < 32; k++) {
        float hk = __shfl(hn, k, 32);
        ua = fmaf(W1[s * 67 + k],      hk, ua);
        va = fmaf(W1[s * 67 + 32 + k], hk, va);
    }
    uacc = ua; vacc = va;
}

__device__ __forceinline__ void readout_row(int s, int j, float hn,
    const float* __restrict__ R1, const float* __restrict__ rb1,
    const float* __restrict__ R2, const float* __restrict__ rb2,
    const float* __restrict__ R3, const float* __restrict__ rb3,
    float* __restrict__ out)
{
    float a1 = rb1[s];
#pragma unroll 8
    for (int k = 0; k < 32; k++) a1 = fmaf(R1[s * 32 + k], __shfl(hn, k, 32), a1);
    a1 = fmaxf(a1, 0.f);
    float a2 = rb2[s];
#pragma unroll 8
    for (int k = 0; k < 32; k++) a2 = fmaf(R2[s * 32 + k], __shfl(a1, k, 32), a2);
    a2 = fmaxf(a2, 0.f);
    float a3 = (s < 2) ? rb3[s] : 0.f;
#pragma unroll 8
    for (int k = 0; k < 32; k++) {
        float a2k = __shfl(a2, k, 32);
        if (s < 2) a3 = fmaf(R3[s * 32 + k], a2k, a3);
    }
    if (s < 2) out[j * 2 + s] = sigmoidf_(fmaxf(a3, 0.f));
}

// ---------------------------------------------------------------------------
// k_pre: blocks 0..1023 transpose J -> Jt; blocks 1024..1151 init h, u0, v
// ---------------------------------------------------------------------------
__global__ __launch_bounds__(256) void k_pre(
    const float* __restrict__ J, const float* __restrict__ b,
    const float* __restrict__ W1, const float* __restrict__ b1,
    float* __restrict__ Jt, float* __restrict__ h,
    float* __restrict__ u0, float* __restrict__ v)
{
    __shared__ float tile[32][33];
    const int t = blockIdx.x;
    const int tid = threadIdx.x;
    if (t < 1024) {
        int tx = (t & 31) * 32, ty = (t >> 5) * 32;
        int x = tid & 31, y = tid >> 5;   // y in 0..7
#pragma unroll
        for (int r = 0; r < 4; r++)
            tile[y + 8 * r][x] = J[(size_t)(ty + y + 8 * r) * NN + tx + x];
        __syncthreads();
#pragma unroll
        for (int r = 0; r < 4; r++)
            Jt[(size_t)(tx + y + 8 * r) * NN + ty + x] = tile[x][y + 8 * r];
    } else {
        int idx = (t - 1024) * 256 + tid;   // 0..32767
        int row = idx >> 5, mm = idx & 31;
        float bi = b[row];
        h[idx]  = 0.f;
        u0[idx] = bi * W1[mm * 67 + 65];
        v[idx]  = fmaf(bi, W1[mm * 67 + 66], b1[mm]);
    }
}

// ---------------------------------------------------------------------------
// k_step: one recurrence step. 1024 blocks (one per j) x 256 threads
// (4 waves x 16 tiles of 16 i's). __launch_bounds__(256,4): 4 blocks/CU,
// 16 waves/CU, <=128 VGPR. Software-pipelined prefetch of J/u per tile.
// GRU fused in tail; readout fused when do_out.
// ---------------------------------------------------------------------------
__global__ __launch_bounds__(256, 4) void k_step(
    const float* __restrict__ Jt, const float* __restrict__ W1,
    const float* __restrict__ W2, const float* __restrict__ b2,
    const float* __restrict__ W3, const float* __restrict__ b3,
    const float* __restrict__ Wih, const float* __restrict__ bih,
    const float* __restrict__ bhh, const float* __restrict__ b,
    const float* __restrict__ b1,
    const float* __restrict__ R1, const float* __restrict__ rb1,
    const float* __restrict__ R2, const float* __restrict__ rb2,
    const float* __restrict__ R3, const float* __restrict__ rb3,
    float* __restrict__ h, float* __restrict__ v,
    const float* __restrict__ ui, float* __restrict__ uo,
    float* __restrict__ out, int do_out)
{
    __shared__ unsigned int ybuf[4 * 2 * 320];   // 4 waves x double buffer
    __shared__ float red[4 * 32];

    const int tid = threadIdx.x;
    const int w = tid >> 6;
    const int l = tid & 63;
    const int p = l & 15;
    const int q = l >> 4;
    const int j = blockIdx.x;

    Ctx c; make_ctx(c, p, q, W1, W2, b2, W3, b3);
    const float* Jtrow = Jt + (size_t)j * NN;

    float vv[8];
#pragma unroll
    for (int jj = 0; jj < 8; jj++) vv[jj] = v[j * 32 + q * 8 + jj];

    f32x4 acc0 = {0.f, 0.f, 0.f, 0.f}, acc1 = {0.f, 0.f, 0.f, 0.f};

    // --- prefetch tile 0
    int i0 = w * 256 + p;
    float  jw = Jtrow[i0];
    float4 ua = *(const float4*)(ui + i0 * 32 + q * 8);
    float4 ub = *(const float4*)(ui + i0 * 32 + q * 8 + 4);

#pragma unroll 2
    for (int t = 0; t < 16; ++t) {
        // current tile's operands (already in registers)
        const float  jw_c = jw;
        const float4 ua_c = ua;
        const float4 ub_c = ub;
        if (t < 15) {   // prefetch next tile while computing this one
            const int in = w * 256 + (t + 1) * 16 + p;
            jw = Jtrow[in];
            ua = *(const float4*)(ui + in * 32 + q * 8);
            ub = *(const float4*)(ui + in * 32 + q * 8 + 4);
        }

        float xr[8];
        xr[0] = fmaxf(fmaf(jw_c, c.wj8[0], ua_c.x + vv[0]), 0.f);
        xr[1] = fmaxf(fmaf(jw_c, c.wj8[1], ua_c.y + vv[1]), 0.f);
        xr[2] = fmaxf(fmaf(jw_c, c.wj8[2], ua_c.z + vv[2]), 0.f);
        xr[3] = fmaxf(fmaf(jw_c, c.wj8[3], ua_c.w + vv[3]), 0.f);
        xr[4] = fmaxf(fmaf(jw_c, c.wj8[4], ub_c.x + vv[4]), 0.f);
        xr[5] = fmaxf(fmaf(jw_c, c.wj8[5], ub_c.y + vv[5]), 0.f);
        xr[6] = fmaxf(fmaf(jw_c, c.wj8[6], ub_c.z + vv[6]), 0.f);
        xr[7] = fmaxf(fmaf(jw_c, c.wj8[7], ub_c.w + vv[7]), 0.f);

        union BU { u32x4 u4; bf16x8 v; unsigned int d[4]; } bx;
#pragma unroll
        for (int cc = 0; cc < 4; cc++) bx.d[cc] = pk_bf16(xr[2 * cc], xr[2 * cc + 1]);

        f32x4 c0 = __builtin_amdgcn_mfma_f32_16x16x32_bf16(c.w2a0, bx.v, c.b2v0, 0, 0, 0);
        f32x4 c1 = __builtin_amdgcn_mfma_f32_16x16x32_bf16(c.w2a1, bx.v, c.b2v1, 0, 0, 0);

        unsigned int* yb = ybuf + w * 640 + (t & 1) * 320;
        yb[p * 20 + q * 2 + 0]     = pk_bf16(fmaxf(c0[0], 0.f), fmaxf(c0[1], 0.f));
        yb[p * 20 + q * 2 + 1]     = pk_bf16(fmaxf(c0[2], 0.f), fmaxf(c0[3], 0.f));
        yb[p * 20 + 8 + q * 2 + 0] = pk_bf16(fmaxf(c1[0], 0.f), fmaxf(c1[1], 0.f));
        yb[p * 20 + 8 + q * 2 + 1] = pk_bf16(fmaxf(c1[2], 0.f), fmaxf(c1[3], 0.f));

        union BU yrd;
        yrd.u4 = *(const u32x4*)(yb + p * 20 + q * 4);

        f32x4 e0 = __builtin_amdgcn_mfma_f32_16x16x32_bf16(c.w3a0, yrd.v, c.b3v0, 0, 0, 0);
        f32x4 e1 = __builtin_amdgcn_mfma_f32_16x16x32_bf16(c.w3a1, yrd.v, c.b3v1, 0, 0, 0);
#pragma unroll
        for (int r = 0; r < 4; r++) {
            acc0[r] += fmaxf(e0[r], 0.f);
            acc1[r] += fmaxf(e1[r], 0.f);
        }
    }

    // reduce over p (lane bits 0..3), then over waves via LDS
#pragma unroll
    for (int bit = 1; bit < 16; bit <<= 1) {
#pragma unroll
        for (int r = 0; r < 4; r++) {
            acc0[r] += __shfl_xor(acc0[r], bit);
            acc1[r] += __shfl_xor(acc1[r], bit);
        }
    }
    if (p == 0) {
#pragma unroll
        for (int r = 0; r < 4; r++) {
            red[w * 32 + q * 4 + r]      = acc0[r];
            red[w * 32 + 16 + q * 4 + r] = acc1[r];
        }
    }
    __syncthreads();

    if (tid < 32) {
        const int s = tid;
        float mval = red[s] + red[32 + s] + red[64 + s] + red[96 + s];
        float hn, uacc, vacc;
        gru_row(s, h[j * 32 + s], mval, b[j], Wih, bih, bhh, W1, b1, hn, uacc, vacc);
        h[j * 32 + s] = hn;
        v[j * 32 + s] = vacc;
        uo[j * 32 + s] = uacc;
        if (do_out) readout_row(s, j, hn, R1, rb1, R2, rb2, R3, rb3, out);
    }
}

// ---------------------------------------------------------------------------
extern "C" void kernel_launch(void* const* d_in, const int* in_sizes, int n_in,
                              void* d_out, int out_size, void* d_ws, size_t ws_size,
                              hipStream_t stream)
{
    const float* J   = (const float*)d_in[0];
    const float* b   = (const float*)d_in[1];
    const float* W1  = (const float*)d_in[2];
    const float* b1  = (const float*)d_in[3];
    const float* W2  = (const float*)d_in[4];
    const float* b2  = (const float*)d_in[5];
    const float* W3  = (const float*)d_in[6];
    const float* b3  = (const float*)d_in[7];
    const float* Wih = (const float*)d_in[8];
    const float* bih = (const float*)d_in[9];
    const float* bhh = (const float*)d_in[10];
    const float* R1  = (const float*)d_in[11];
    const float* rb1 = (const float*)d_in[12];
    const float* R2  = (const float*)d_in[13];
    const float* rb2 = (const float*)d_in[14];
    const float* R3  = (const float*)d_in[15];
    const float* rb3 = (const float*)d_in[16];

    float* out = (float*)d_out;
    float* ws  = (float*)d_ws;
    float* h  = ws;
    float* v  = ws + 32768;
    float* u0 = ws + 65536;
    float* u1 = ws + 98304;
    float* Jt = ws + 131072;

    k_pre<<<1152, 256, 0, stream>>>(J, b, W1, b1, Jt, h, u0, v);
    for (int s = 0; s < 5; s++) {
        const float* ui = (s & 1) ? u1 : u0;
        float*       uo = (s & 1) ? u0 : u1;
        k_step<<<1024, 256, 0, stream>>>(Jt, W1, W2, b2, W3, b3, Wih, bih,
                                         bhh, b, b1, R1, rb1, R2, rb2, R3,
                                         rb3, h, v, ui, uo, out,
                                         (s == 4) ? 1 : 0);
    }
}

// Round 6
// 223.238 us; speedup vs baseline: 1.0081x; 1.0081x over previous
//
#include <hip/hip_runtime.h>
#include <math.h>

#define NN 1024

typedef __attribute__((ext_vector_type(8))) short bf16x8;
typedef __attribute__((ext_vector_type(4))) float f32x4;
typedef __attribute__((ext_vector_type(4))) unsigned int u32x4;

__device__ __forceinline__ float sigmoidf_(float x) { return 1.0f / (1.0f + __expf(-x)); }

// RNE bf16 round; pack two floats into one dword (lo = a, hi = b)
__device__ __forceinline__ unsigned int pk_bf16(float a, float b) {
    unsigned int ua = __float_as_uint(a), ub = __float_as_uint(b);
    ua += 0x7fffu + ((ua >> 16) & 1u);
    ub += 0x7fffu + ((ub >> 16) & 1u);
    return (ua >> 16) | (ub & 0xffff0000u);
}
__device__ __forceinline__ unsigned short f2bf_rne(float a) {
    unsigned int ua = __float_as_uint(a);
    ua += 0x7fffu + ((ua >> 16) & 1u);
    return (unsigned short)(ua >> 16);
}

struct Ctx {
    bf16x8 w2a0, w2a1, w3a0, w3a1;
    f32x4 b2v0, b2v1, b3v0, b3v1;   // biases folded into MFMA C operand
    float wj8[8];
};

__device__ __forceinline__ void make_ctx(Ctx& c, int p, int q,
    const float* __restrict__ W1, const float* __restrict__ W2,
    const float* __restrict__ b2, const float* __restrict__ W3,
    const float* __restrict__ b3)
{
    union FU { bf16x8 v; unsigned short s[8]; } t0, t1, t2, t3;
#pragma unroll
    for (int jj = 0; jj < 8; jj++) {
        int k = q * 8 + jj;
        t0.s[jj] = f2bf_rne(W2[p * 32 + k]);
        t1.s[jj] = f2bf_rne(W2[(16 + p) * 32 + k]);
        t2.s[jj] = f2bf_rne(W3[p * 32 + k]);
        t3.s[jj] = f2bf_rne(W3[(16 + p) * 32 + k]);
        c.wj8[jj] = W1[k * 67 + 64];
    }
    c.w2a0 = t0.v; c.w2a1 = t1.v; c.w3a0 = t2.v; c.w3a1 = t3.v;
#pragma unroll
    for (int r = 0; r < 4; r++) {
        c.b2v0[r] = b2[q * 4 + r];  c.b2v1[r] = b2[16 + q * 4 + r];
        c.b3v0[r] = b3[q * 4 + r];  c.b3v1[r] = b3[16 + q * 4 + r];
    }
}

__device__ __forceinline__ void gru_row(int s, float hval, float mval, float bj,
    const float* __restrict__ Wih, const float* __restrict__ bih,
    const float* __restrict__ bhh, const float* __restrict__ W1,
    const float* __restrict__ b1, float& hn, float& uacc, float& vacc)
{
    float g0 = bih[s], g1 = bih[32 + s], g2 = bih[64 + s];
#pragma unroll 8
    for (int k = 0; k < 32; k++) {
        float hk = __shfl(hval, k, 32);
        float mk = __shfl(mval, k, 32);
        g0 = fmaf(Wih[s * 64 + k],             hk, g0);
        g0 = fmaf(Wih[s * 64 + 32 + k],        mk, g0);
        g1 = fmaf(Wih[(32 + s) * 64 + k],      hk, g1);
        g1 = fmaf(Wih[(32 + s) * 64 + 32 + k], mk, g1);
        g2 = fmaf(Wih[(64 + s) * 64 + k],      hk, g2);
        g2 = fmaf(Wih[(64 + s) * 64 + 32 + k], mk, g2);
    }
    float r = sigmoidf_(g0 + bhh[s]);
    float z = sigmoidf_(g1 + bhh[32 + s]);
    float n = tanhf(g2 + r * bhh[64 + s]);
    hn = (1.0f - z) * n;
    float ua = bj * W1[s * 67 + 65];
    float va = fmaf(bj, W1[s * 67 + 66], b1[s]);
#pragma unroll 8
    for (int k = 0; k < 32; k++) {
        float hk = __shfl(hn, k, 32);
        ua = fmaf(W1[s * 67 + k],      hk, ua);
        va = fmaf(W1[s * 67 + 32 + k], hk, va);
    }
    uacc = ua; vacc = va;
}

__device__ __forceinline__ void readout_row(int s, int j, float hn,
    const float* __restrict__ R1, const float* __restrict__ rb1,
    const float* __restrict__ R2, const float* __restrict__ rb2,
    const float* __restrict__ R3, const float* __restrict__ rb3,
    float* __restrict__ out)
{
    float a1 = rb1[s];
#pragma unroll 8
    for (int k = 0; k < 32; k++) a1 = fmaf(R1[s * 32 + k], __shfl(hn, k, 32), a1);
    a1 = fmaxf(a1, 0.f);
    float a2 = rb2[s];
#pragma unroll 8
    for (int k = 0; k < 32; k++) a2 = fmaf(R2[s * 32 + k], __shfl(a1, k, 32), a2);
    a2 = fmaxf(a2, 0.f);
    float a3 = (s < 2) ? rb3[s] : 0.f;
#pragma unroll 8
    for (int k = 0; k < 32; k++) {
        float a2k = __shfl(a2, k, 32);
        if (s < 2) a3 = fmaf(R3[s * 32 + k], a2k, a3);
    }
    if (s < 2) out[j * 2 + s] = sigmoidf_(fmaxf(a3, 0.f));
}

// ---------------------------------------------------------------------------
// k_pre: blocks 0..1023 transpose J -> Jt; blocks 1024..1151 init h, u0, v
// ---------------------------------------------------------------------------
__global__ __launch_bounds__(256) void k_pre(
    const float* __restrict__ J, const float* __restrict__ b,
    const float* __restrict__ W1, const float* __restrict__ b1,
    float* __restrict__ Jt, float* __restrict__ h,
    float* __restrict__ u0, float* __restrict__ v)
{
    __shared__ float tile[32][33];
    const int t = blockIdx.x;
    const int tid = threadIdx.x;
    if (t < 1024) {
        int tx = (t & 31) * 32, ty = (t >> 5) * 32;
        int x = tid & 31, y = tid >> 5;   // y in 0..7
#pragma unroll
        for (int r = 0; r < 4; r++)
            tile[y + 8 * r][x] = J[(size_t)(ty + y + 8 * r) * NN + tx + x];
        __syncthreads();
#pragma unroll
        for (int r = 0; r < 4; r++)
            Jt[(size_t)(tx + y + 8 * r) * NN + ty + x] = tile[x][y + 8 * r];
    } else {
        int idx = (t - 1024) * 256 + tid;   // 0..32767
        int row = idx >> 5, mm = idx & 31;
        float bi = b[row];
        h[idx]  = 0.f;
        u0[idx] = bi * W1[mm * 67 + 65];
        v[idx]  = fmaf(bi, W1[mm * 67 + 66], b1[mm]);
    }
}

// ---------------------------------------------------------------------------
// k_step: one recurrence step. 1024 blocks (one per j) x 256 threads
// (4 waves x 16 tiles of 16 i's).  C-layout -> B-layout transform done with
// 8 ds_bpermute + 4 cndmask (register-only), NOT an LDS round-trip: no
// lgkmcnt(0) drain, no bank conflicts, and the scheduler can pipeline tiles.
// ---------------------------------------------------------------------------
__global__ __launch_bounds__(256, 4) void k_step(
    const float* __restrict__ Jt, const float* __restrict__ W1,
    const float* __restrict__ W2, const float* __restrict__ b2,
    const float* __restrict__ W3, const float* __restrict__ b3,
    const float* __restrict__ Wih, const float* __restrict__ bih,
    const float* __restrict__ bhh, const float* __restrict__ b,
    const float* __restrict__ b1,
    const float* __restrict__ R1, const float* __restrict__ rb1,
    const float* __restrict__ R2, const float* __restrict__ rb2,
    const float* __restrict__ R3, const float* __restrict__ rb3,
    float* __restrict__ h, float* __restrict__ v,
    const float* __restrict__ ui, float* __restrict__ uo,
    float* __restrict__ out, int do_out)
{
    __shared__ float red[4 * 32];

    const int tid = threadIdx.x;
    const int w = tid >> 6;
    const int l = tid & 63;
    const int p = l & 15;
    const int q = l >> 4;
    const int j = blockIdx.x;

    Ctx c; make_ctx(c, p, q, W1, W2, b2, W3, b3);
    const float* Jtrow = Jt + (size_t)j * NN;

    float vv[8];
#pragma unroll
    for (int jj = 0; jj < 8; jj++) vv[jj] = v[j * 32 + q * 8 + jj];

    // bpermute byte-addresses for the C->B layout exchange.
    // reader (p,q) pulls from source lanes  p + 32*(q&1)  and  +16.
    const int s0 = (p | ((l & 16) << 1)) << 2;
    const int s1 = s0 + 64;
    const bool qlo = (l & 32) == 0;   // q < 2

    f32x4 acc0 = {0.f, 0.f, 0.f, 0.f}, acc1 = {0.f, 0.f, 0.f, 0.f};

    // prefetch tile 0
    int i0 = w * 256 + p;
    float  jw = Jtrow[i0];
    float4 ua = *(const float4*)(ui + i0 * 32 + q * 8);
    float4 ub = *(const float4*)(ui + i0 * 32 + q * 8 + 4);

#pragma unroll 2
    for (int t = 0; t < 16; ++t) {
        const float  jw_c = jw;
        const float4 ua_c = ua;
        const float4 ub_c = ub;
        if (t < 15) {
            const int in = w * 256 + (t + 1) * 16 + p;
            jw = Jtrow[in];
            ua = *(const float4*)(ui + in * 32 + q * 8);
            ub = *(const float4*)(ui + in * 32 + q * 8 + 4);
        }

        float xr[8];
        xr[0] = fmaxf(fmaf(jw_c, c.wj8[0], ua_c.x + vv[0]), 0.f);
        xr[1] = fmaxf(fmaf(jw_c, c.wj8[1], ua_c.y + vv[1]), 0.f);
        xr[2] = fmaxf(fmaf(jw_c, c.wj8[2], ua_c.z + vv[2]), 0.f);
        xr[3] = fmaxf(fmaf(jw_c, c.wj8[3], ua_c.w + vv[3]), 0.f);
        xr[4] = fmaxf(fmaf(jw_c, c.wj8[4], ub_c.x + vv[4]), 0.f);
        xr[5] = fmaxf(fmaf(jw_c, c.wj8[5], ub_c.y + vv[5]), 0.f);
        xr[6] = fmaxf(fmaf(jw_c, c.wj8[6], ub_c.z + vv[6]), 0.f);
        xr[7] = fmaxf(fmaf(jw_c, c.wj8[7], ub_c.w + vv[7]), 0.f);

        union BU { u32x4 u4; bf16x8 v; unsigned int d[4]; } bx;
#pragma unroll
        for (int cc = 0; cc < 4; cc++) bx.d[cc] = pk_bf16(xr[2 * cc], xr[2 * cc + 1]);

        f32x4 c0 = __builtin_amdgcn_mfma_f32_16x16x32_bf16(c.w2a0, bx.v, c.b2v0, 0, 0, 0);
        f32x4 c1 = __builtin_amdgcn_mfma_f32_16x16x32_bf16(c.w2a1, bx.v, c.b2v1, 0, 0, 0);

        // Y = relu(D2); pack rows (f,f+1) per dword in C-layout
        const int d0 = (int)pk_bf16(fmaxf(c0[0], 0.f), fmaxf(c0[1], 0.f));
        const int d1 = (int)pk_bf16(fmaxf(c0[2], 0.f), fmaxf(c0[3], 0.f));
        const int d2 = (int)pk_bf16(fmaxf(c1[0], 0.f), fmaxf(c1[1], 0.f));
        const int d3 = (int)pk_bf16(fmaxf(c1[2], 0.f), fmaxf(c1[3], 0.f));

        // C-layout -> B-layout: pull the two source lanes' dword pairs
        const int A0 = __builtin_amdgcn_ds_bpermute(s0, d0);
        const int A1 = __builtin_amdgcn_ds_bpermute(s0, d1);
        const int A2 = __builtin_amdgcn_ds_bpermute(s1, d0);
        const int A3 = __builtin_amdgcn_ds_bpermute(s1, d1);
        const int B0 = __builtin_amdgcn_ds_bpermute(s0, d2);
        const int B1 = __builtin_amdgcn_ds_bpermute(s0, d3);
        const int B2 = __builtin_amdgcn_ds_bpermute(s1, d2);
        const int B3 = __builtin_amdgcn_ds_bpermute(s1, d3);

        union BU yr;
        yr.d[0] = (unsigned)(qlo ? A0 : B0);
        yr.d[1] = (unsigned)(qlo ? A1 : B1);
        yr.d[2] = (unsigned)(qlo ? A2 : B2);
        yr.d[3] = (unsigned)(qlo ? A3 : B3);

        f32x4 e0 = __builtin_amdgcn_mfma_f32_16x16x32_bf16(c.w3a0, yr.v, c.b3v0, 0, 0, 0);
        f32x4 e1 = __builtin_amdgcn_mfma_f32_16x16x32_bf16(c.w3a1, yr.v, c.b3v1, 0, 0, 0);
#pragma unroll
        for (int r = 0; r < 4; r++) {
            acc0[r] += fmaxf(e0[r], 0.f);
            acc1[r] += fmaxf(e1[r], 0.f);
        }
    }

    // reduce over p (lane bits 0..3), then over waves via LDS
#pragma unroll
    for (int bit = 1; bit < 16; bit <<= 1) {
#pragma unroll
        for (int r = 0; r < 4; r++) {
            acc0[r] += __shfl_xor(acc0[r], bit);
            acc1[r] += __shfl_xor(acc1[r], bit);
        }
    }
    if (p == 0) {
#pragma unroll
        for (int r = 0; r < 4; r++) {
            red[w * 32 + q * 4 + r]      = acc0[r];
            red[w * 32 + 16 + q * 4 + r] = acc1[r];
        }
    }
    __syncthreads();

    if (tid < 32) {
        const int s = tid;
        float mval = red[s] + red[32 + s] + red[64 + s] + red[96 + s];
        float hn, uacc, vacc;
        gru_row(s, h[j * 32 + s], mval, b[j], Wih, bih, bhh, W1, b1, hn, uacc, vacc);
        h[j * 32 + s] = hn;
        v[j * 32 + s] = vacc;
        uo[j * 32 + s] = uacc;
        if (do_out) readout_row(s, j, hn, R1, rb1, R2, rb2, R3, rb3, out);
    }
}

// ---------------------------------------------------------------------------
extern "C" void kernel_launch(void* const* d_in, const int* in_sizes, int n_in,
                              void* d_out, int out_size, void* d_ws, size_t ws_size,
                              hipStream_t stream)
{
    const float* J   = (const float*)d_in[0];
    const float* b   = (const float*)d_in[1];
    const float* W1  = (const float*)d_in[2];
    const float* b1  = (const float*)d_in[3];
    const float* W2  = (const float*)d_in[4];
    const float* b2  = (const float*)d_in[5];
    const float* W3  = (const float*)d_in[6];
    const float* b3  = (const float*)d_in[7];
    const float* Wih = (const float*)d_in[8];
    const float* bih = (const float*)d_in[9];
    const float* bhh = (const float*)d_in[10];
    const float* R1  = (const float*)d_in[11];
    const float* rb1 = (const float*)d_in[12];
    const float* R2  = (const float*)d_in[13];
    const float* rb2 = (const float*)d_in[14];
    const float* R3  = (const float*)d_in[15];
    const float* rb3 = (const float*)d_in[16];

    float* out = (float*)d_out;
    float* ws  = (float*)d_ws;
    float* h  = ws;
    float* v  = ws + 32768;
    float* u0 = ws + 65536;
    float* u1 = ws + 98304;
    float* Jt = ws + 131072;

    k_pre<<<1152, 256, 0, stream>>>(J, b, W1, b1, Jt, h, u0, v);
    for (int s = 0; s < 5; s++) {
        const float* ui = (s & 1) ? u1 : u0;
        float*       uo = (s & 1) ? u0 : u1;
        k_step<<<1024, 256, 0, stream>>>(Jt, W1, W2, b2, W3, b3, Wih, bih,
                                         bhh, b, b1, R1, rb1, R2, rb2, R3,
                                         rb3, h, v, ui, uo, out,
                                         (s == 4) ? 1 : 0);
    }
}